// Round 1
// baseline (137.221 us; speedup 1.0000x reference)
//
#include <hip/hip_runtime.h>

// DWT db4, 6 levels, zero-padding mode. Input x:[64, 262144] f32.
// out = concat(cA6[64,4102], cD6[64,4102], cD5[64,8198], cD4[64,16390],
//              cD3[64,32774], cD2[64,65541], cD1[64,131075]) flat.
//
// Fully fused: one block = one row x one tile of TT=64 level-6 outputs.
// All 6 levels computed in LDS (ping-pong); details written to global at
// each level over the tile's owned (non-halo) range only.
//
// dwt step: out[i] = sum_{t=0..7} filt[t] * x[2i+1-t], zeros outside [0,N).
// M_k = (N_{k-1}+7)//2. Tile base recurrence: b_{k-1} = 2*b_k - 6.

#define NTHREADS 256
#define TT 64
#define LEN0 (64*TT + 378)  // 4474
#define LEN1 (32*TT + 186)  // 2234
#define LEN2 (16*TT + 90)   // 1114
#define LEN3 (8*TT + 42)    // 554
#define LEN4 (4*TT + 18)    // 274
#define LEN5 (2*TT + 6)     // 134
#define LEN6 (TT)           // 64

#define N0 262144
#define M1 131075
#define M2 65541
#define M3 32774
#define M4 16390
#define M5 8198
#define M6 4102

// output offsets (elements), B=64
#define OFF_A6 ((size_t)0)
#define OFF_D6 ((size_t)262528)
#define OFF_D5 ((size_t)525056)
#define OFF_D4 ((size_t)1049728)
#define OFF_D3 ((size_t)2098688)
#define OFF_D2 ((size_t)4196224)
#define OFF_D1 ((size_t)8390848)

__device__ __constant__ float c_lo[8] = {
    -0.010597401784997278f, 0.032883011666982945f, 0.030841381835986965f,
    -0.18703481171888114f, -0.02798376941698385f, 0.6308807679295904f,
    0.7148465705525415f, 0.23037781330885523f};
__device__ __constant__ float c_hi[8] = {
    -0.23037781330885523f, 0.7148465705525415f, -0.6308807679295904f,
    -0.02798376941698385f, 0.18703481171888114f, 0.030841381835986965f,
    -0.032883011666982945f, -0.010597401784997278f};

// One DWT level entirely in LDS. s: source (prev-level cA, local coords with
// global base 2*base-6), d: dest cA buffer (len entries). Entries whose global
// index is outside [0,M) are stored as 0 (they feed the next level's zeros).
// Detail coeffs written to global for the owned range l >= cOff (g < M).
__device__ inline void dwt_step_lds(const float* __restrict__ s,
                                    float* __restrict__ d,
                                    int base, int len, int M, int cOff,
                                    float* __restrict__ dglob, int tid) {
  for (int l = tid; l < len; l += NTHREADS) {
    int g = base + l;
    float a = 0.f, dt = 0.f;
    if (g >= 0 && g < M) {
#pragma unroll
      for (int t = 0; t < 8; ++t) {
        float v = s[2 * l + 7 - t];
        a = fmaf(c_lo[t], v, a);
        dt = fmaf(c_hi[t], v, dt);
      }
    }
    d[l] = a;
    if (l >= cOff && g < M) dglob[g] = dt;  // l>=cOff implies g>=0
  }
}

__global__ __launch_bounds__(NTHREADS) void dwt6_kernel(
    const float* __restrict__ x, float* __restrict__ out) {
  const int p = blockIdx.x;    // tile index along level-6 outputs
  const int row = blockIdx.y;  // batch row
  const int tid = threadIdx.x;

  __shared__ float bufA[LEN0];
  __shared__ float bufB[LEN1];

  const int b6 = p * TT;
  const int b5 = 2 * b6 - 6;
  const int b4 = 2 * b5 - 6;
  const int b3 = 2 * b4 - 6;
  const int b2 = 2 * b3 - 6;
  const int b1 = 2 * b2 - 6;
  const int b0 = 2 * b1 - 6;

  // stage input tile (+halo) into LDS, zero outside [0, N0)
  const float* __restrict__ xr = x + (size_t)row * N0;
  for (int l = tid; l < LEN0; l += NTHREADS) {
    int g = b0 + l;
    bufA[l] = (g >= 0 && g < N0) ? xr[g] : 0.0f;
  }
  __syncthreads();

  dwt_step_lds(bufA, bufB, b1, LEN1, M1, 186, out + OFF_D1 + (size_t)row * M1, tid);
  __syncthreads();
  dwt_step_lds(bufB, bufA, b2, LEN2, M2, 90, out + OFF_D2 + (size_t)row * M2, tid);
  __syncthreads();
  dwt_step_lds(bufA, bufB, b3, LEN3, M3, 42, out + OFF_D3 + (size_t)row * M3, tid);
  __syncthreads();
  dwt_step_lds(bufB, bufA, b4, LEN4, M4, 18, out + OFF_D4 + (size_t)row * M4, tid);
  __syncthreads();
  dwt_step_lds(bufA, bufB, b5, LEN5, M5, 6, out + OFF_D5 + (size_t)row * M5, tid);
  __syncthreads();

  // level 6: read cA5 from bufB, write cA6 + cD6 straight to global
  for (int l = tid; l < LEN6; l += NTHREADS) {
    int g = b6 + l;
    if (g < M6) {
      float a = 0.f, dt = 0.f;
#pragma unroll
      for (int t = 0; t < 8; ++t) {
        float v = bufB[2 * l + 7 - t];
        a = fmaf(c_lo[t], v, a);
        dt = fmaf(c_hi[t], v, dt);
      }
      out[OFF_A6 + (size_t)row * M6 + g] = a;
      out[OFF_D6 + (size_t)row * M6 + g] = dt;
    }
  }
}

extern "C" void kernel_launch(void* const* d_in, const int* in_sizes, int n_in,
                              void* d_out, int out_size, void* d_ws, size_t ws_size,
                              hipStream_t stream) {
  const float* x = (const float*)d_in[0];
  float* out = (float*)d_out;
  // 65 tiles cover M6=4102 level-6 outputs (64*65=4160), 64 rows
  dim3 grid(65, 64);
  dwt6_kernel<<<grid, NTHREADS, 0, stream>>>(x, out);
}

// Round 2
// 123.715 us; speedup vs baseline: 1.1092x; 1.1092x over previous
//
#include <hip/hip_runtime.h>

// DWT db4, 6 levels, zero-padding mode. Input x:[64, 262144] f32.
// out = concat(cA6[64,4102], cD6[64,4102], cD5[64,8198], cD4[64,16390],
//              cD3[64,32774], cD2[64,65541], cD1[64,131075]) flat.
//
// Fused single kernel; block = (tile p of 64 level-6 outputs) x (row).
// Interior tiles p=1..63 take a checked-free vectorized fast path:
//   - staging: float2 global loads (tile base b0 == 2 mod 4)
//   - each thread computes 4 consecutive outputs from 4x float4 LDS reads
//   - cA written back as float4; details stored scalar (coalesced via L2)
//   - full detail range written (halo duplicates are value-identical)
// Edge tiles p=0,64 use the scalar bounds-checked path (proven R1).
//
// dwt step: out[i] = sum_t filt[t]*x[2i+1-t]; in local coords (src buffer
// base = 2*b-6) the window is s[2l .. 2l+7]: out_l = sum_m RFILT[m]*s[2l+m].

#define NT 256
#define TT 64
#define LEN0 4474  // 64*TT+378
#define LEN1 2234
#define LEN2 1114
#define LEN3 554
#define LEN4 274
#define LEN5 134

#define N0 262144
#define M1 131075
#define M2 65541
#define M3 32774
#define M4 16390
#define M5 8198
#define M6 4102

#define OFF_A6 ((size_t)0)
#define OFF_D6 ((size_t)262528)
#define OFF_D5 ((size_t)525056)
#define OFF_D4 ((size_t)1049728)
#define OFF_D3 ((size_t)2098688)
#define OFF_D2 ((size_t)4196224)
#define OFF_D1 ((size_t)8390848)

// reversed db4 filters: out_l = sum_m RLO[m]*s[2l+m]
__device__ __constant__ float RLO[8] = {
    0.23037781330885523f, 0.7148465705525415f, 0.6308807679295904f,
    -0.02798376941698385f, -0.18703481171888114f, 0.030841381835986965f,
    0.032883011666982945f, -0.010597401784997278f};
__device__ __constant__ float RHI[8] = {
    -0.010597401784997278f, -0.032883011666982945f, 0.030841381835986965f,
    0.18703481171888114f, -0.02798376941698385f, -0.6308807679295904f,
    0.7148465705525415f, -0.23037781330885523f};

// ---------------- fast path (interior, no bounds checks) ----------------
// s4: src cA buffer (f4 view), d4: dst cA buffer, dg: detail global base
// (already offset by b_k). LEN = valid output count, NC = ceil(LEN/4).
template <int LEN, int NC>
__device__ __forceinline__ void level_fast(const float4* __restrict__ s4,
                                           float4* __restrict__ d4,
                                           float* __restrict__ dg) {
  for (int c = threadIdx.x; c < NC; c += NT) {
    float4 q0 = s4[2 * c + 0];
    float4 q1 = s4[2 * c + 1];
    float4 q2 = s4[2 * c + 2];
    float4 q3 = s4[2 * c + 3];
    float w[16] = {q0.x, q0.y, q0.z, q0.w, q1.x, q1.y, q1.z, q1.w,
                   q2.x, q2.y, q2.z, q2.w, q3.x, q3.y, q3.z, q3.w};
    float a[4], d[4];
#pragma unroll
    for (int j = 0; j < 4; ++j) {
      float aa = 0.f, dd = 0.f;
#pragma unroll
      for (int m = 0; m < 8; ++m) {
        aa = fmaf(RLO[m], w[2 * j + m], aa);
        dd = fmaf(RHI[m], w[2 * j + m], dd);
      }
      a[j] = aa;
      d[j] = dd;
    }
    d4[c] = make_float4(a[0], a[1], a[2], a[3]);
    const int l0 = 4 * c;
    if (l0 + 4 <= LEN) {
#pragma unroll
      for (int j = 0; j < 4; ++j) dg[l0 + j] = d[j];
    } else {
#pragma unroll
      for (int j = 0; j < 4; ++j)
        if (l0 + j < LEN) dg[l0 + j] = d[j];
    }
  }
}

// ---------------- slow path (edge tiles, bounds-checked) ----------------
__device__ inline void dwt_step_slow(const float* __restrict__ s,
                                     float* __restrict__ d, int base, int len,
                                     int M, int cOff, float* __restrict__ dglob,
                                     int tid) {
  for (int l = tid; l < len; l += NT) {
    int g = base + l;
    float a = 0.f, dt = 0.f;
    if (g >= 0 && g < M) {
#pragma unroll
      for (int m = 0; m < 8; ++m) {
        float v = s[2 * l + m];
        a = fmaf(RLO[m], v, a);
        dt = fmaf(RHI[m], v, dt);
      }
    }
    d[l] = a;
    if (l >= cOff && g < M) dglob[g] = dt;
  }
}

__global__ __launch_bounds__(NT, 5) void dwt6_kernel(const float* __restrict__ x,
                                                     float* __restrict__ out) {
  const int p = blockIdx.x;
  const int row = blockIdx.y;
  const int tid = threadIdx.x;

  __shared__ float4 bufA4[1120];  // 4480 floats
  __shared__ float4 bufB4[560];   // 2240 floats
  float* bufA = (float*)bufA4;
  float* bufB = (float*)bufB4;

  const int b6 = p * TT;
  const int b5 = 2 * b6 - 6;
  const int b4 = 2 * b5 - 6;
  const int b3 = 2 * b4 - 6;
  const int b2 = 2 * b3 - 6;
  const int b1 = 2 * b2 - 6;
  const int b0 = 2 * b1 - 6;

  const size_t r1 = (size_t)row * M1, r2 = (size_t)row * M2,
               r3 = (size_t)row * M3, r4 = (size_t)row * M4,
               r5 = (size_t)row * M5, r6 = (size_t)row * M6;

  if (p >= 1 && p <= 63) {
    // ---- fast path: everything provably in-bounds ----
    // stage x[b0 .. b0+4473] via float2 (b0 even; b0 == 2 mod 4)
    const float2* __restrict__ xs = (const float2*)(x + (size_t)row * N0 + b0);
    float2* __restrict__ bA2 = (float2*)bufA;
    for (int m = tid; m < LEN0 / 2; m += NT) bA2[m] = xs[m];
    __syncthreads();

    level_fast<LEN1, 559>(bufA4, bufB4, out + OFF_D1 + r1 + b1);
    __syncthreads();
    level_fast<LEN2, 279>(bufB4, bufA4, out + OFF_D2 + r2 + b2);
    __syncthreads();
    level_fast<LEN3, 139>(bufA4, bufB4, out + OFF_D3 + r3 + b3);
    __syncthreads();
    level_fast<LEN4, 69>(bufB4, bufA4, out + OFF_D4 + r4 + b4);
    __syncthreads();
    level_fast<LEN5, 34>(bufA4, bufB4, out + OFF_D5 + r5 + b5);
    __syncthreads();

    // level 6: 64 outputs, 16 chunks, write cA6+cD6 straight to global
    float* __restrict__ ga = out + OFF_A6 + r6 + b6;
    float* __restrict__ gd = out + OFF_D6 + r6 + b6;
    for (int c = tid; c < 16; c += NT) {
      float4 q0 = bufB4[2 * c + 0];
      float4 q1 = bufB4[2 * c + 1];
      float4 q2 = bufB4[2 * c + 2];
      float4 q3 = bufB4[2 * c + 3];
      float w[16] = {q0.x, q0.y, q0.z, q0.w, q1.x, q1.y, q1.z, q1.w,
                     q2.x, q2.y, q2.z, q2.w, q3.x, q3.y, q3.z, q3.w};
#pragma unroll
      for (int j = 0; j < 4; ++j) {
        float aa = 0.f, dd = 0.f;
#pragma unroll
        for (int m = 0; m < 8; ++m) {
          aa = fmaf(RLO[m], w[2 * j + m], aa);
          dd = fmaf(RHI[m], w[2 * j + m], dd);
        }
        ga[4 * c + j] = aa;
        gd[4 * c + j] = dd;
      }
    }
  } else {
    // ---- slow path: p == 0 or p == 64 ----
    const float* __restrict__ xr = x + (size_t)row * N0;
    for (int l = tid; l < LEN0; l += NT) {
      int g = b0 + l;
      bufA[l] = (g >= 0 && g < N0) ? xr[g] : 0.0f;
    }
    __syncthreads();

    dwt_step_slow(bufA, bufB, b1, LEN1, M1, 186, out + OFF_D1 + r1, tid);
    __syncthreads();
    dwt_step_slow(bufB, bufA, b2, LEN2, M2, 90, out + OFF_D2 + r2, tid);
    __syncthreads();
    dwt_step_slow(bufA, bufB, b3, LEN3, M3, 42, out + OFF_D3 + r3, tid);
    __syncthreads();
    dwt_step_slow(bufB, bufA, b4, LEN4, M4, 18, out + OFF_D4 + r4, tid);
    __syncthreads();
    dwt_step_slow(bufA, bufB, b5, LEN5, M5, 6, out + OFF_D5 + r5, tid);
    __syncthreads();

    for (int l = tid; l < TT; l += NT) {
      int g = b6 + l;
      if (g < M6) {
        float a = 0.f, dt = 0.f;
#pragma unroll
        for (int m = 0; m < 8; ++m) {
          float v = bufB[2 * l + m];
          a = fmaf(RLO[m], v, a);
          dt = fmaf(RHI[m], v, dt);
        }
        out[OFF_A6 + r6 + g] = a;
        out[OFF_D6 + r6 + g] = dt;
      }
    }
  }
}

extern "C" void kernel_launch(void* const* d_in, const int* in_sizes, int n_in,
                              void* d_out, int out_size, void* d_ws,
                              size_t ws_size, hipStream_t stream) {
  const float* x = (const float*)d_in[0];
  float* out = (float*)d_out;
  dim3 grid(65, 64);
  dwt6_kernel<<<grid, NT, 0, stream>>>(x, out);
}

// Round 3
// 113.891 us; speedup vs baseline: 1.2048x; 1.0863x over previous
//
#include <hip/hip_runtime.h>

// DWT db4, 6 levels, zero mode. x:[64, 262144] f32 ->
// concat(cA6, cD6, cD5, cD4, cD3, cD2, cD1) flat.
//
// R3: TT=32 tiles (8 blocks/CU = 32 waves, 100% occupancy cap),
// de-interleaved even/odd LDS layout (all LDS reads stride-1 b128,
// writes stride-1 b64), float4 staging, non-temporal output stores.
// Interior tiles p=1..127 fast path; p=0,128 bounds-checked slow path.
//
// dwt: out[g] = sum_m RFILT[m]*x[2g-6+m]. With even/odd split E[k]=v[2k],
// O[k]=v[2k+1]: out_l = sum_t RLO[2t]*E[l+S+t] + RLO[2t+1]*O[l+S+t].

#define NT 256
#define TT 32
#define LEN0 2426  // 64*TT + 378
#define LEN1 1210
#define LEN2 602
#define LEN3 298
#define LEN4 146
#define LEN5 70

#define N0 262144
#define M1 131075
#define M2 65541
#define M3 32774
#define M4 16390
#define M5 8198
#define M6 4102

#define OFF_A6 ((size_t)0)
#define OFF_D6 ((size_t)262528)
#define OFF_D5 ((size_t)525056)
#define OFF_D4 ((size_t)1049728)
#define OFF_D3 ((size_t)2098688)
#define OFF_D2 ((size_t)4196224)
#define OFF_D1 ((size_t)8390848)

// LDS float layout: A-E [0,1216) A-O [1216,2432) B-E [2432,3040) B-O [3040,3648)
#define AE 0
#define AO 1216
#define BE 2432
#define BO 3040
#define LDS_FLOATS 3648

__device__ __constant__ float RLO[8] = {
    0.23037781330885523f, 0.7148465705525415f, 0.6308807679295904f,
    -0.02798376941698385f, -0.18703481171888114f, 0.030841381835986965f,
    0.032883011666982945f, -0.010597401784997278f};
__device__ __constant__ float RHI[8] = {
    -0.010597401784997278f, -0.032883011666982945f, 0.030841381835986965f,
    0.18703481171888114f, -0.02798376941698385f, -0.6308807679295904f,
    0.7148465705525415f, -0.23037781330885523f};

// One fast level: src de-interleaved (sE4/sO4), dst de-interleaved
// (dE2/dO2), details -> dg (global, nontemporal). SHIFT=1 for level 1
// (staged buffer starts 2 before the window base), 0 otherwise.
template <int LEN, int NC, int SHIFT>
__device__ __forceinline__ void level_fast(const float4* __restrict__ sE4,
                                           const float4* __restrict__ sO4,
                                           float2* __restrict__ dE2,
                                           float2* __restrict__ dO2,
                                           float* __restrict__ dg) {
  for (int c = threadIdx.x; c < NC; c += NT) {
    float4 e0 = sE4[c], e1 = sE4[c + 1];
    float4 o0 = sO4[c], o1 = sO4[c + 1];
    float e[8] = {e0.x, e0.y, e0.z, e0.w, e1.x, e1.y, e1.z, e1.w};
    float o[8] = {o0.x, o0.y, o0.z, o0.w, o1.x, o1.y, o1.z, o1.w};
    float a[4], d[4];
#pragma unroll
    for (int j = 0; j < 4; ++j) {
      float aa = 0.f, dd = 0.f;
#pragma unroll
      for (int t = 0; t < 4; ++t) {
        float ev = e[j + t + SHIFT];
        float ov = o[j + t + SHIFT];
        aa = fmaf(RLO[2 * t], ev, aa);
        aa = fmaf(RLO[2 * t + 1], ov, aa);
        dd = fmaf(RHI[2 * t], ev, dd);
        dd = fmaf(RHI[2 * t + 1], ov, dd);
      }
      a[j] = aa;
      d[j] = dd;
    }
    dE2[c] = make_float2(a[0], a[2]);
    dO2[c] = make_float2(a[1], a[3]);
    const int l0 = 4 * c;
    if (l0 + 4 <= LEN) {
#pragma unroll
      for (int j = 0; j < 4; ++j) __builtin_nontemporal_store(d[j], dg + l0 + j);
    } else {
#pragma unroll
      for (int j = 0; j < 4; ++j)
        if (l0 + j < LEN) __builtin_nontemporal_store(d[j], dg + l0 + j);
    }
  }
}

// slow path (edge tiles): flat layout, bounds-checked
__device__ inline void dwt_step_slow(const float* __restrict__ s,
                                     float* __restrict__ d, int base, int len,
                                     int M, int cOff, float* __restrict__ dglob,
                                     int tid) {
  for (int l = tid; l < len; l += NT) {
    int g = base + l;
    float a = 0.f, dt = 0.f;
    if (g >= 0 && g < M) {
#pragma unroll
      for (int m = 0; m < 8; ++m) {
        float v = s[2 * l + m];
        a = fmaf(RLO[m], v, a);
        dt = fmaf(RHI[m], v, dt);
      }
    }
    d[l] = a;
    if (l >= cOff && g < M) dglob[g] = dt;
  }
}

__global__ __launch_bounds__(NT, 8) void dwt6_kernel(const float* __restrict__ x,
                                                     float* __restrict__ out) {
  const int p = blockIdx.x;
  const int row = blockIdx.y;
  const int tid = threadIdx.x;

  __shared__ float lds[LDS_FLOATS];

  const int b6 = p * TT;
  const int b5 = 2 * b6 - 6;
  const int b4 = 2 * b5 - 6;
  const int b3 = 2 * b4 - 6;
  const int b2 = 2 * b3 - 6;
  const int b1 = 2 * b2 - 6;
  const int b0 = 2 * b1 - 6;  // 2048p - 378

  const size_t r1 = (size_t)row * M1, r2 = (size_t)row * M2,
               r3 = (size_t)row * M3, r4 = (size_t)row * M4,
               r5 = (size_t)row * M5, r6 = (size_t)row * M6;

  if (p >= 1 && p <= 127) {
    // ---- fast path: all levels provably in-bounds ----
    // stage x[sb .. sb+2427], sb = b0-2 (== 0 mod 4) into A (de-interleaved)
    const float4* __restrict__ xs4 =
        (const float4*)(x + (size_t)row * N0 + (b0 - 2));
    float2* __restrict__ aE2 = (float2*)(lds + AE);
    float2* __restrict__ aO2 = (float2*)(lds + AO);
    for (int m = tid; m < 607; m += NT) {
      float4 v = xs4[m];
      aE2[m] = make_float2(v.x, v.z);
      aO2[m] = make_float2(v.y, v.w);
    }
    __syncthreads();

    const float4* aE4 = (const float4*)(lds + AE);
    const float4* aO4 = (const float4*)(lds + AO);
    const float4* bE4 = (const float4*)(lds + BE);
    const float4* bO4 = (const float4*)(lds + BO);
    float2* bE2 = (float2*)(lds + BE);
    float2* bO2 = (float2*)(lds + BO);

    level_fast<LEN1, 303, 1>(aE4, aO4, bE2, bO2, out + OFF_D1 + r1 + b1);
    __syncthreads();
    level_fast<LEN2, 151, 0>(bE4, bO4, aE2, aO2, out + OFF_D2 + r2 + b2);
    __syncthreads();
    level_fast<LEN3, 75, 0>(aE4, aO4, bE2, bO2, out + OFF_D3 + r3 + b3);
    __syncthreads();
    level_fast<LEN4, 37, 0>(bE4, bO4, aE2, aO2, out + OFF_D4 + r4 + b4);
    __syncthreads();
    level_fast<LEN5, 18, 0>(aE4, aO4, bE2, bO2, out + OFF_D5 + r5 + b5);
    __syncthreads();

    // level 6: 32 outputs, 8 chunks, straight to global
    float* __restrict__ ga = out + OFF_A6 + r6 + b6;
    float* __restrict__ gd = out + OFF_D6 + r6 + b6;
    for (int c = tid; c < 8; c += NT) {
      float4 e0 = bE4[c], e1 = bE4[c + 1];
      float4 o0 = bO4[c], o1 = bO4[c + 1];
      float e[8] = {e0.x, e0.y, e0.z, e0.w, e1.x, e1.y, e1.z, e1.w};
      float o[8] = {o0.x, o0.y, o0.z, o0.w, o1.x, o1.y, o1.z, o1.w};
#pragma unroll
      for (int j = 0; j < 4; ++j) {
        float aa = 0.f, dd = 0.f;
#pragma unroll
        for (int t = 0; t < 4; ++t) {
          aa = fmaf(RLO[2 * t], e[j + t], aa);
          aa = fmaf(RLO[2 * t + 1], o[j + t], aa);
          dd = fmaf(RHI[2 * t], e[j + t], dd);
          dd = fmaf(RHI[2 * t + 1], o[j + t], dd);
        }
        __builtin_nontemporal_store(aa, ga + 4 * c + j);
        __builtin_nontemporal_store(dd, gd + 4 * c + j);
      }
    }
  } else {
    // ---- slow path: p == 0 or p == 128 ----
    float* bufA = lds;         // LEN0 = 2426 <= 2432
    float* bufB = lds + BE;    // LEN1 = 1210 <= 1216
    const float* __restrict__ xr = x + (size_t)row * N0;
    for (int l = tid; l < LEN0; l += NT) {
      int g = b0 + l;
      bufA[l] = (g >= 0 && g < N0) ? xr[g] : 0.0f;
    }
    __syncthreads();

    dwt_step_slow(bufA, bufB, b1, LEN1, M1, 186, out + OFF_D1 + r1, tid);
    __syncthreads();
    dwt_step_slow(bufB, bufA, b2, LEN2, M2, 90, out + OFF_D2 + r2, tid);
    __syncthreads();
    dwt_step_slow(bufA, bufB, b3, LEN3, M3, 42, out + OFF_D3 + r3, tid);
    __syncthreads();
    dwt_step_slow(bufB, bufA, b4, LEN4, M4, 18, out + OFF_D4 + r4, tid);
    __syncthreads();
    dwt_step_slow(bufA, bufB, b5, LEN5, M5, 6, out + OFF_D5 + r5, tid);
    __syncthreads();

    for (int l = tid; l < TT; l += NT) {
      int g = b6 + l;
      if (g < M6) {
        float a = 0.f, dt = 0.f;
#pragma unroll
        for (int m = 0; m < 8; ++m) {
          float v = bufB[2 * l + m];
          a = fmaf(RLO[m], v, a);
          dt = fmaf(RHI[m], v, dt);
        }
        out[OFF_A6 + r6 + g] = a;
        out[OFF_D6 + r6 + g] = dt;
      }
    }
  }
}

extern "C" void kernel_launch(void* const* d_in, const int* in_sizes, int n_in,
                              void* d_out, int out_size, void* d_ws,
                              size_t ws_size, hipStream_t stream) {
  const float* x = (const float*)d_in[0];
  float* out = (float*)d_out;
  dim3 grid(129, 64);  // 129 tiles of 32 level-6 outputs cover M6=4102
  dwt6_kernel<<<grid, NT, 0, stream>>>(x, out);
}